// Round 7
// baseline (249.241 us; speedup 1.0000x reference)
//
#include <hip/hip_runtime.h>
#include <hip/hip_bf16.h>
#include <stdint.h>

typedef __bf16 bf16;
typedef bf16 bf16x8 __attribute__((ext_vector_type(8)));
typedef bf16 bf16x4 __attribute__((ext_vector_type(4)));
typedef float f32x4 __attribute__((ext_vector_type(4)));

#define MFMA16(a, b, c) __builtin_amdgcn_mfma_f32_16x16x32_bf16(a, b, c, 0, 0, 0)

static __device__ __forceinline__ bf16 f2b(float f) { return (bf16)f; }
static __device__ __forceinline__ float b2f(bf16 v) { return (float)v; }

// async global->LDS, 16B per lane. dst is wave-uniform base; HW adds lane*16.
static __device__ __forceinline__ void gload16(const void* src, void* dst) {
    __builtin_amdgcn_global_load_lds(
        (const __attribute__((address_space(1))) uint32_t*)src,
        (__attribute__((address_space(3))) uint32_t*)dst, 16, 0, 0);
}

// ---------------- fused fp32 -> bf16 conversion (x, Wq, Wk, Wv in one launch) ------------
__global__ void cvt_all(const float* __restrict__ x,  const float* __restrict__ wq,
                        const float* __restrict__ wk, const float* __restrict__ wv,
                        bf16* __restrict__ xb,  bf16* __restrict__ wqb,
                        bf16* __restrict__ wkb, bf16* __restrict__ wvb) {
    int i = blockIdx.x * blockDim.x + threadIdx.x;   // float4 index, 0..5242879
    const float* src; bf16* dst; int off;
    if (i < 2097152)      { src = x;  dst = xb;  off = i; }
    else if (i < 3145728) { src = wq; dst = wqb; off = i - 2097152; }
    else if (i < 4194304) { src = wk; dst = wkb; off = i - 3145728; }
    else                  { src = wv; dst = wvb; off = i - 4194304; }
    float4 v = reinterpret_cast<const float4*>(src)[off];
    bf16x4 o;
    o[0] = f2b(v.x); o[1] = f2b(v.y); o[2] = f2b(v.z); o[3] = f2b(v.w);
    reinterpret_cast<bf16x4*>(dst)[off] = o;
}

// ---------------- RoPE cos/sin table: tbl[s][i] = {cos,sin}(s * theta_i) ----------------
__global__ void rope_table(float2* __restrict__ tbl) {
    int t = blockIdx.x * blockDim.x + threadIdx.x;   // 0 .. 2048*64-1
    int i = t & 63;
    int s = t >> 6;
    float theta = expf(-9.210340371976184f * (float)(2 * i) * (1.0f / 128.0f));
    float freq = (float)s * theta;
    float sv, cv;
    sincosf(freq, &sv, &cv);
    tbl[t] = make_float2(cv, sv);
}

// ---------------- fused QKV GEMM: 8-phase counted-vmcnt schedule ----------------
// BM=256 BN=128 BK=64, 512 threads = 8 waves (4M x 2N), per-wave 64x64 output.
// LDS 96KB: As[2][256x64] + Bs[2][128x64], XOR-swizzled rows (8 slots of 16B).
// Per K-tile: 4 phases {ds_read subtile | stage event | barrier | lgkmcnt(0) |
// 8 MFMA (setprio) | barrier}. Stage events (3 loads each) at ph1/ph4/ph5/ph8;
// vmcnt(3) at ph4/ph8 only — loads never drained to 0 in the main loop.
// z=0: Q (+rope, scale=log2e/sqrt(128)); z=1: K (+rope); z=2: V transposed.
__global__ __launch_bounds__(512, 2) void gemm_qkv(const bf16* __restrict__ X,
                                                   const bf16* __restrict__ Wq,
                                                   const bf16* __restrict__ Wk,
                                                   const bf16* __restrict__ Wv,
                                                   bf16* __restrict__ Qm,
                                                   bf16* __restrict__ Km,
                                                   bf16* __restrict__ Vt,
                                                   const float2* __restrict__ tbl) {
    const int K = 2048;
    __shared__ bf16 As[2][256 * 64];   // 64KB
    __shared__ bf16 Bs[2][128 * 64];   // 32KB

    // block decode: z = round (0..2); within round, XCD-swizzle the 256 tiles
    const int bid = blockIdx.x;
    const int z = bid >> 8;
    int j = bid & 255;
    j = (j & 7) * 32 + (j >> 3);       // 256 % 8 == 0: simple bijective swizzle
    const int mx = j >> 4, ny = j & 15;
    const int rbase = mx * 256, cbase = ny * 128;

    const bf16* W = (z == 0) ? Wq : (z == 1) ? Wk : Wv;

    const int tid  = threadIdx.x;
    const int lane = tid & 63;
    const int w    = tid >> 6;         // 0..7
    const int wm   = w >> 1;           // 0..3 (M)
    const int wn   = w & 1;            // 0..1 (N)
    const int l15  = lane & 15;
    const int l4   = lane >> 4;

    const int srow  = lane >> 3;       // staging: row within 8-row chunk
    const int sslot = lane & 7;        // physical 16B slot

    // stage A-half h (128 rows) of K-tile `tile` into buf: 2 chunks/wave
    auto stageA = [&](int buf, int tile, int h) {
        int kt = tile * 64;
#pragma unroll
        for (int i = 0; i < 2; ++i) {
            int c   = h * 16 + w * 2 + i;        // chunk 0..31
            int row = c * 8 + srow;              // 0..255
            int gsl = sslot ^ (row & 7);
            gload16(&X[(size_t)(rbase + row) * K + kt + gsl * 8],
                    (char*)As[buf] + c * 1024);
        }
    };
    // stage B-half h (64 rows): 1 chunk/wave
    auto stageB = [&](int buf, int tile, int h) {
        int kt  = tile * 64;
        int c   = h * 8 + w;                     // chunk 0..15
        int row = c * 8 + srow;                  // 0..127
        int gsl = sslot ^ (row & 7);
        gload16(&W[(size_t)(cbase + row) * K + kt + gsl * 8],
                (char*)Bs[buf] + c * 1024);
    };

    auto rdA = [&](int buf, int mi, int ks) {
        int r    = wm * 64 + mi * 16 + l15;
        int phys = (ks * 4 + l4) ^ (r & 7);
        return *reinterpret_cast<const bf16x8*>((char*)As[buf] + r * 128 + phys * 16);
    };
    auto rdB = [&](int buf, int ni, int ks) {
        int r    = wn * 64 + ni * 16 + l15;
        int phys = (ks * 4 + l4) ^ (r & 7);
        return *reinterpret_cast<const bf16x8*>((char*)Bs[buf] + r * 128 + phys * 16);
    };

    f32x4 acc[4][4] = {};

#define PHASE_OPEN                                                  \
    __builtin_amdgcn_s_barrier();                                   \
    asm volatile("s_waitcnt lgkmcnt(0)" ::: "memory");              \
    __builtin_amdgcn_s_setprio(1)
#define PHASE_CLOSE                                                 \
    __builtin_amdgcn_s_setprio(0);                                  \
    __builtin_amdgcn_s_barrier();                                   \
    asm volatile("" ::: "memory")
// 8 MFMAs of one quadrant; ks0 across all 4 accs then ks1 (no back-to-back dep)
#define MFMA_QUAD(ar0, ar1, br0, br1, m0, m1, n0, n1)               \
    acc[m0][n0] = MFMA16(ar0[0], br0[0], acc[m0][n0]);              \
    acc[m0][n1] = MFMA16(ar0[0], br1[0], acc[m0][n1]);              \
    acc[m1][n0] = MFMA16(ar1[0], br0[0], acc[m1][n0]);              \
    acc[m1][n1] = MFMA16(ar1[0], br1[0], acc[m1][n1]);              \
    acc[m0][n0] = MFMA16(ar0[1], br0[1], acc[m0][n0]);              \
    acc[m0][n1] = MFMA16(ar0[1], br1[1], acc[m0][n1]);              \
    acc[m1][n0] = MFMA16(ar1[1], br0[1], acc[m1][n0]);              \
    acc[m1][n1] = MFMA16(ar1[1], br1[1], acc[m1][n1]);

    // prologue: tile0 full -> buf0; tile1 h0 -> buf1. 9 loads/thread.
    stageA(0, 0, 0); stageB(0, 0, 0);
    stageA(0, 0, 1); stageB(0, 0, 1);
    stageA(1, 1, 0); stageB(1, 1, 0);
    asm volatile("s_waitcnt vmcnt(3)" ::: "memory");   // tile0's 6 loads landed
    __builtin_amdgcn_s_barrier();
    asm volatile("" ::: "memory");

    for (int it = 0; it < 16; ++it) {
        const int t1 = 2 * it + 1;
        const int t2 = (2 * it + 2 < 32) ? 2 * it + 2 : 31;   // clamp last-iter prefetch
        const int t3 = (2 * it + 3 < 32) ? 2 * it + 3 : 31;
        bf16x8 a0[2], a1[2], a2[2], a3[2], b0[2], b1[2], b2[2], b3[2];

        // ========== K-tile 2it (buf0) ==========
        // ph1: Q(M01,N01); E1 = tile(2it+1) h1 -> buf1
        a0[0] = rdA(0, 0, 0); a0[1] = rdA(0, 0, 1);
        a1[0] = rdA(0, 1, 0); a1[1] = rdA(0, 1, 1);
        b0[0] = rdB(0, 0, 0); b0[1] = rdB(0, 0, 1);
        b1[0] = rdB(0, 1, 0); b1[1] = rdB(0, 1, 1);
        stageA(1, t1, 1); stageB(1, t1, 1);
        PHASE_OPEN; MFMA_QUAD(a0, a1, b0, b1, 0, 1, 0, 1); PHASE_CLOSE;
        // ph2: Q(M01,N23)
        b2[0] = rdB(0, 2, 0); b2[1] = rdB(0, 2, 1);
        b3[0] = rdB(0, 3, 0); b3[1] = rdB(0, 3, 1);
        PHASE_OPEN; MFMA_QUAD(a0, a1, b2, b3, 0, 1, 2, 3); PHASE_CLOSE;
        // ph3: Q(M23,N01)
        a2[0] = rdA(0, 2, 0); a2[1] = rdA(0, 2, 1);
        a3[0] = rdA(0, 3, 0); a3[1] = rdA(0, 3, 1);
        PHASE_OPEN; MFMA_QUAD(a2, a3, b0, b1, 2, 3, 0, 1); PHASE_CLOSE;
        // ph4: Q(M23,N23); E4 = tile t2 h0 -> buf0; W_B: vmcnt(3) seals tile 2it+1
        stageA(0, t2, 0); stageB(0, t2, 0);
        asm volatile("s_waitcnt vmcnt(3)" ::: "memory");
        PHASE_OPEN; MFMA_QUAD(a2, a3, b2, b3, 2, 3, 2, 3); PHASE_CLOSE;

        // ========== K-tile 2it+1 (buf1) ==========
        // ph5: Q(M01,N01); E5 = tile t2 h1 -> buf0
        a0[0] = rdA(1, 0, 0); a0[1] = rdA(1, 0, 1);
        a1[0] = rdA(1, 1, 0); a1[1] = rdA(1, 1, 1);
        b0[0] = rdB(1, 0, 0); b0[1] = rdB(1, 0, 1);
        b1[0] = rdB(1, 1, 0); b1[1] = rdB(1, 1, 1);
        stageA(0, t2, 1); stageB(0, t2, 1);
        PHASE_OPEN; MFMA_QUAD(a0, a1, b0, b1, 0, 1, 0, 1); PHASE_CLOSE;
        // ph6: Q(M01,N23)
        b2[0] = rdB(1, 2, 0); b2[1] = rdB(1, 2, 1);
        b3[0] = rdB(1, 3, 0); b3[1] = rdB(1, 3, 1);
        PHASE_OPEN; MFMA_QUAD(a0, a1, b2, b3, 0, 1, 2, 3); PHASE_CLOSE;
        // ph7: Q(M23,N01)
        a2[0] = rdA(1, 2, 0); a2[1] = rdA(1, 2, 1);
        a3[0] = rdA(1, 3, 0); a3[1] = rdA(1, 3, 1);
        PHASE_OPEN; MFMA_QUAD(a2, a3, b0, b1, 2, 3, 0, 1); PHASE_CLOSE;
        // ph8: Q(M23,N23); E8 = tile t3 h0 -> buf1; W_A: vmcnt(3) seals tile t2
        stageA(1, t3, 0); stageB(1, t3, 0);
        asm volatile("s_waitcnt vmcnt(3)" ::: "memory");
        PHASE_OPEN; MFMA_QUAD(a2, a3, b2, b3, 2, 3, 2, 3); PHASE_CLOSE;
    }
#undef PHASE_OPEN
#undef PHASE_CLOSE
#undef MFMA_QUAD

    asm volatile("s_waitcnt vmcnt(0)" ::: "memory");   // drain DMA overhang before end

    if (z < 2) {
        bf16* Y = (z == 0) ? Qm : Km;
        const float scale = (z == 0) ? 0.1275174396094198f : 1.0f;  // log2e/sqrt(128) | 1
        const int odd = l15 & 1;
#pragma unroll
        for (int mi = 0; mi < 4; ++mi) {
            int r0 = rbase + wm * 64 + mi * 16 + l4 * 4;
#pragma unroll
            for (int i = 0; i < 4; ++i) {
                int r = r0 + i;
                int b = r >> 11, s = r & 2047;
#pragma unroll
                for (int ni = 0; ni < 4; ++ni) {
                    int n = cbase + wn * 64 + ni * 16 + l15;
                    int h = n >> 7, d = n & 127;
                    float v = acc[mi][ni][i];
                    float p = __shfl_xor(v, 1);
                    float2 cs = tbl[(s << 6) + (d >> 1)];
                    float res = v * cs.x + (odd ? p : -p) * cs.y;
                    Y[(((size_t)b * 16 + h) * 2048 + s) * 128 + d] = f2b(res * scale);
                }
            }
        }
    } else {
#pragma unroll
        for (int mi = 0; mi < 4; ++mi) {
            int r0 = rbase + wm * 64 + mi * 16 + l4 * 4;
            int b = r0 >> 11, s = r0 & 2047;
#pragma unroll
            for (int ni = 0; ni < 4; ++ni) {
                int n = cbase + wn * 64 + ni * 16 + l15;
                int h = n >> 7, d = n & 127;
                bf16x4 o;
#pragma unroll
                for (int i = 0; i < 4; ++i) o[i] = f2b(acc[mi][ni][i]);
                *reinterpret_cast<bf16x4*>(&Vt[(((size_t)b * 16 + h) * 128 + d) * 2048 + s]) = o;
            }
        }
    }
}

// ---------------- causal flash attention v4 (unchanged from round 6) ----------------
__global__ __launch_bounds__(256) void flash_attn(const bf16* __restrict__ Q,
                                                  const bf16* __restrict__ Km,
                                                  const bf16* __restrict__ Vt,
                                                  float* __restrict__ out) {
    __shared__ bf16 Ksh[64 * 128];
    __shared__ bf16 Vsh[128 * 64];
    __shared__ bf16 Psh[4][16 * 64];

    const int tid  = threadIdx.x;
    const int lane = tid & 63;
    const int w    = tid >> 6;
    const int l15  = lane & 15;
    const int l4   = lane >> 4;

    const int bx  = blockIdx.x;
    const int g   = (bx >> 5) & 7;
    const int seg = bx >> 8;
    const int qt  = (seg == 0) ? 31 - g : (seg == 1) ? g : (seg == 2) ? 23 - g : 8 + g;
    const int bh  = bx & 31;
    const int b   = bh >> 4, h = bh & 15;

    const bf16* Qb = Q  + (size_t)bh * 2048 * 128;
    const bf16* Kb = Km + (size_t)bh * 2048 * 128;
    const bf16* Vb = Vt + (size_t)bh * 128 * 2048;
    const int rw = qt * 64 + w * 16;

    auto stage = [&](int kvb) {
#pragma unroll
        for (int c4 = 0; c4 < 4; ++c4) {
            int c  = w * 4 + c4;
            int kr = c * 4 + (lane >> 4);
            int ks = (lane & 15) ^ (kr & 7);
            gload16((const char*)Kb + ((size_t)(kvb + kr) * 128 + ks * 8) * 2,
                    (char*)Ksh + c * 1024);
            int vr = c * 8 + (lane >> 3);
            int vs = (lane & 7) ^ (vr & 7);
            gload16((const char*)Vb + ((size_t)vr * 2048 + kvb + vs * 8) * 2,
                    (char*)Vsh + c * 1024);
        }
    };

    bf16x8 qf[4];
#pragma unroll
    for (int ks = 0; ks < 4; ++ks)
        qf[ks] = *reinterpret_cast<const bf16x8*>(
            &Qb[(size_t)(rw + l15) * 128 + ks * 32 + l4 * 8]);

    f32x4 o[8] = {};
    float mrow[4], lrow[4];
#pragma unroll
    for (int i = 0; i < 4; ++i) { mrow[i] = -1e30f; lrow[i] = 0.0f; }

    char* pw = (char*)Psh[w];

    for (int t = 0; t <= qt; ++t) {
        const int kvb = t * 64;
        __syncthreads();
        stage(kvb);
        __syncthreads();

        const char* kb = (const char*)Ksh;
        f32x4 sacc[4] = {};
        __builtin_amdgcn_s_setprio(1);
#pragma unroll
        for (int ns = 0; ns < 4; ++ns) {
            int r = ns * 16 + l15;
#pragma unroll
            for (int ks = 0; ks < 4; ++ks) {
                int phys = (ks * 4 + l4) ^ (r & 7);
                bf16x8 kf = *reinterpret_cast<const bf16x8*>(kb + r * 256 + phys * 16);
                sacc[ns] = MFMA16(qf[ks], kf, sacc[ns]);
            }
        }
        __builtin_amdgcn_s_setprio(0);

        if (t == qt) {
#pragma unroll
            for (int ns = 0; ns < 4; ++ns) {
                int col = kvb + ns * 16 + l15;
#pragma unroll
                for (int i = 0; i < 4; ++i) {
                    int row = rw + l4 * 4 + i;
                    if (col > row) sacc[ns][i] = -1e30f;
                }
            }
        }
#pragma unroll
        for (int i = 0; i < 4; ++i) {
            float sm = fmaxf(fmaxf(sacc[0][i], sacc[1][i]), fmaxf(sacc[2][i], sacc[3][i]));
            sm = fmaxf(sm, __shfl_xor(sm, 1));
            sm = fmaxf(sm, __shfl_xor(sm, 2));
            sm = fmaxf(sm, __shfl_xor(sm, 4));
            sm = fmaxf(sm, __shfl_xor(sm, 8));
            float nm    = fmaxf(mrow[i], sm);
            float alpha = __builtin_amdgcn_exp2f(mrow[i] - nm);
            mrow[i] = nm;
            float ps = 0.0f;
            int r = l4 * 4 + i;
            int f = r & 7;
#pragma unroll
            for (int ns = 0; ns < 4; ++ns) {
                float p = __builtin_amdgcn_exp2f(sacc[ns][i] - nm);
                ps += p;
                int col  = ns * 16 + l15;
                int slot = (col >> 3) ^ f;
                *(bf16*)(pw + r * 128 + slot * 16 + (col & 7) * 2) = f2b(p);
            }
            ps += __shfl_xor(ps, 1);
            ps += __shfl_xor(ps, 2);
            ps += __shfl_xor(ps, 4);
            ps += __shfl_xor(ps, 8);
            lrow[i] = lrow[i] * alpha + ps;
#pragma unroll
            for (int ds = 0; ds < 8; ++ds) o[ds][i] *= alpha;
        }
        asm volatile("s_waitcnt lgkmcnt(0)" ::: "memory");
        __builtin_amdgcn_sched_barrier(0);
        const char* vb = (const char*)Vsh;
        __builtin_amdgcn_s_setprio(1);
#pragma unroll
        for (int k2 = 0; k2 < 2; ++k2) {
            int pr   = l15;
            int phys = (k2 * 4 + l4) ^ (pr & 7);
            bf16x8 pa = *reinterpret_cast<const bf16x8*>(pw + pr * 128 + phys * 16);
#pragma unroll
            for (int ds = 0; ds < 8; ++ds) {
                int d     = ds * 16 + l15;
                int physv = (k2 * 4 + l4) ^ (d & 7);
                bf16x8 vf = *reinterpret_cast<const bf16x8*>(vb + d * 128 + physv * 16);
                o[ds] = MFMA16(pa, vf, o[ds]);
            }
        }
        __builtin_amdgcn_s_setprio(0);
    }

#pragma unroll
    for (int i = 0; i < 4; ++i) {
        float inv = 1.0f / lrow[i];
        int row = rw + l4 * 4 + i;
#pragma unroll
        for (int ds = 0; ds < 8; ++ds)
            out[((size_t)b * 2048 + row) * 2048 + h * 128 + ds * 16 + l15] = o[ds][i] * inv;
    }
}

extern "C" void kernel_launch(void* const* d_in, const int* in_sizes, int n_in,
                              void* d_out, int out_size, void* d_ws, size_t ws_size,
                              hipStream_t stream) {
    const float* x  = (const float*)d_in[0];
    const float* Wq = (const float*)d_in[1];
    const float* Wk = (const float*)d_in[2];
    const float* Wv = (const float*)d_in[3];
    float* out = (float*)d_out;
    char* ws = (char*)d_ws;

    bf16* xb   = (bf16*)(ws + 0);
    bf16* wqb  = (bf16*)(ws + 16777216);
    bf16* wkb  = (bf16*)(ws + 25165824);
    bf16* wvb  = (bf16*)(ws + 33554432);
    bf16* Qm   = (bf16*)(ws + 41943040);
    bf16* Km   = (bf16*)(ws + 58720256);
    bf16* Vt   = (bf16*)(ws + 75497472);
    float2* tbl = (float2*)(ws + 92274688);

    cvt_all<<<20480, 256, 0, stream>>>(x, Wq, Wk, Wv, xb, wqb, wkb, wvb);
    rope_table<<<512, 256, 0, stream>>>(tbl);

    gemm_qkv<<<768, 512, 0, stream>>>(xb, wqb, wkb, wvb, Qm, Km, Vt, tbl);

    flash_attn<<<1024, 256, 0, stream>>>(Qm, Km, Vt, out);
}

// Round 8
// 240.527 us; speedup vs baseline: 1.0362x; 1.0362x over previous
//
#include <hip/hip_runtime.h>
#include <hip/hip_bf16.h>
#include <stdint.h>

typedef __bf16 bf16;
typedef bf16 bf16x8 __attribute__((ext_vector_type(8)));
typedef bf16 bf16x4 __attribute__((ext_vector_type(4)));
typedef float f32x4 __attribute__((ext_vector_type(4)));

#define MFMA16(a, b, c) __builtin_amdgcn_mfma_f32_16x16x32_bf16(a, b, c, 0, 0, 0)

static __device__ __forceinline__ bf16 f2b(float f) { return (bf16)f; }
static __device__ __forceinline__ float b2f(bf16 v) { return (float)v; }

// async global->LDS, 16B per lane. dst is wave-uniform base; HW adds lane*16.
static __device__ __forceinline__ void gload16(const void* src, void* dst) {
    __builtin_amdgcn_global_load_lds(
        (const __attribute__((address_space(1))) uint32_t*)src,
        (__attribute__((address_space(3))) uint32_t*)dst, 16, 0, 0);
}

// ---------------- fused fp32 -> bf16 conversion ----------------
__global__ void cvt_all(const float* __restrict__ x,  const float* __restrict__ wq,
                        const float* __restrict__ wk, const float* __restrict__ wv,
                        bf16* __restrict__ xb,  bf16* __restrict__ wqb,
                        bf16* __restrict__ wkb, bf16* __restrict__ wvb) {
    int i = blockIdx.x * blockDim.x + threadIdx.x;
    const float* src; bf16* dst; int off;
    if (i < 2097152)      { src = x;  dst = xb;  off = i; }
    else if (i < 3145728) { src = wq; dst = wqb; off = i - 2097152; }
    else if (i < 4194304) { src = wk; dst = wkb; off = i - 3145728; }
    else                  { src = wv; dst = wvb; off = i - 4194304; }
    float4 v = reinterpret_cast<const float4*>(src)[off];
    bf16x4 o;
    o[0] = f2b(v.x); o[1] = f2b(v.y); o[2] = f2b(v.z); o[3] = f2b(v.w);
    reinterpret_cast<bf16x4*>(dst)[off] = o;
}

// ---------------- RoPE cos/sin table ----------------
__global__ void rope_table(float2* __restrict__ tbl) {
    int t = blockIdx.x * blockDim.x + threadIdx.x;
    int i = t & 63;
    int s = t >> 6;
    float theta = expf(-9.210340371976184f * (float)(2 * i) * (1.0f / 128.0f));
    float freq = (float)s * theta;
    float sv, cv;
    sincosf(freq, &sv, &cv);
    tbl[t] = make_float2(cv, sv);
}

// ---------------- fused QKV GEMM: 16-MFMA phases, counted vmcnt(3) ----------------
// BM=128 BN=256 BK=64, 512 thr = 8 waves (2M x 4N), per-wave 64x64, acc[4][4].
// 2 phases per K-tile (N-half each, 16 MFMA). Buffer staged only in its 2 idle
// phases (3+3 loads), sealed by vmcnt(3)+barrier one phase before first read.
// Grid 768 = 3 exact rounds of 256 CUs. LDS 96KB (As 2x16K + Bs 2x32K), XOR-swz.
__global__ __launch_bounds__(512, 2) void gemm_qkv(const bf16* __restrict__ X,
                                                   const bf16* __restrict__ Wq,
                                                   const bf16* __restrict__ Wk,
                                                   const bf16* __restrict__ Wv,
                                                   bf16* __restrict__ Qm,
                                                   bf16* __restrict__ Km,
                                                   bf16* __restrict__ Vt,
                                                   const float2* __restrict__ tbl) {
    const int K = 2048;
    __shared__ bf16 As[2][128 * 64];   // 2 x 16KB
    __shared__ bf16 Bs[2][256 * 64];   // 2 x 32KB

    const int bid = blockIdx.x;
    const int wg  = (bid & 7) * 96 + (bid >> 3);   // XCD-contiguous, bijective (768%8==0)
    const int z   = wg >> 8;                       // 0..2
    const int t   = wg & 255;
    const int rbase = (t >> 3) * 128;              // 32 M-tiles
    const int cbase = (t & 7) * 256;               // 8 N-tiles

    const bf16* W = (z == 0) ? Wq : (z == 1) ? Wk : Wv;

    const int tid  = threadIdx.x;
    const int lane = tid & 63;
    const int w    = tid >> 6;      // 0..7
    const int wm   = w >> 2;        // 0..1
    const int wn   = w & 3;         // 0..3
    const int l15  = lane & 15;
    const int l4   = lane >> 4;
    const int srow  = lane >> 3;
    const int sslot = lane & 7;

    auto stageA = [&](int buf, int tile) {   // 2 loads: A full (128 rows)
#pragma unroll
        for (int i = 0; i < 2; ++i) {
            int c   = w * 2 + i;             // chunk 0..15
            int row = c * 8 + srow;
            int gsl = sslot ^ (row & 7);
            gload16(&X[(size_t)(rbase + row) * K + tile * 64 + gsl * 8],
                    (char*)As[buf] + c * 1024);
        }
    };
    auto stageB1 = [&](int buf, int tile) {  // 1 load: B rows 0..63
        int c   = w;
        int row = c * 8 + srow;
        int gsl = sslot ^ (row & 7);
        gload16(&W[(size_t)(cbase + row) * K + tile * 64 + gsl * 8],
                (char*)Bs[buf] + c * 1024);
    };
    auto stageB2 = [&](int buf, int tile) {  // 3 loads: B rows 64..255
#pragma unroll
        for (int i = 0; i < 3; ++i) {
            int c   = 8 + w * 3 + i;         // chunk 8..31
            int row = c * 8 + srow;
            int gsl = sslot ^ (row & 7);
            gload16(&W[(size_t)(cbase + row) * K + tile * 64 + gsl * 8],
                    (char*)Bs[buf] + c * 1024);
        }
    };
    auto rdA = [&](int buf, int mi, int ks) {
        int r    = wm * 64 + mi * 16 + l15;
        int phys = (ks * 4 + l4) ^ (r & 7);
        return *reinterpret_cast<const bf16x8*>((char*)As[buf] + r * 128 + phys * 16);
    };
    auto rdB = [&](int buf, int ni, int ks) {
        int r    = wn * 64 + ni * 16 + l15;
        int phys = (ks * 4 + l4) ^ (r & 7);
        return *reinterpret_cast<const bf16x8*>((char*)Bs[buf] + r * 128 + phys * 16);
    };

    f32x4 acc[4][4] = {};
    bf16x8 aa[4][2], b0[2], b1[2], b2[2], b3[2];

#define OPEN_PHASE                                              \
    __builtin_amdgcn_s_barrier();                               \
    asm volatile("s_waitcnt lgkmcnt(0)" ::: "memory");          \
    __builtin_amdgcn_sched_barrier(0);                          \
    __builtin_amdgcn_s_setprio(1)
#define CLOSE_PHASE                                             \
    __builtin_amdgcn_s_setprio(0);                              \
    __builtin_amdgcn_s_barrier();                               \
    asm volatile("" ::: "memory")
#define QUAD(B0, B1, C0, C1)                                    \
    _Pragma("unroll")                                           \
    for (int ks = 0; ks < 2; ++ks) {                            \
        _Pragma("unroll")                                       \
        for (int mi = 0; mi < 4; ++mi) {                        \
            acc[mi][C0] = MFMA16(aa[mi][ks], B0[ks], acc[mi][C0]); \
            acc[mi][C1] = MFMA16(aa[mi][ks], B1[ks], acc[mi][C1]); \
        }                                                       \
    }
#define LOAD_TILE(BUF)                                          \
    _Pragma("unroll")                                           \
    for (int mi = 0; mi < 4; ++mi) {                            \
        aa[mi][0] = rdA(BUF, mi, 0); aa[mi][1] = rdA(BUF, mi, 1); \
    }                                                           \
    b0[0] = rdB(BUF, 0, 0); b0[1] = rdB(BUF, 0, 1);             \
    b1[0] = rdB(BUF, 1, 0); b1[1] = rdB(BUF, 1, 1);             \
    b2[0] = rdB(BUF, 2, 0); b2[1] = rdB(BUF, 2, 1);             \
    b3[0] = rdB(BUF, 3, 0); b3[1] = rdB(BUF, 3, 1);

    // prologue: buf0 <- tile0 full (6), buf1 <- tile1 part1 (3); seal tile0
    stageA(0, 0); stageB1(0, 0); stageB2(0, 0);
    stageA(1, 1); stageB1(1, 1);
    asm volatile("s_waitcnt vmcnt(3)" ::: "memory");
    __builtin_amdgcn_s_barrier();
    asm volatile("" ::: "memory");

    for (int it = 0; it < 16; ++it) {
        const int e  = 2 * it, o = e + 1;
        const int e2 = (e + 2 < 32) ? e + 2 : 30;   // clamp: re-stage same data
        const int o2 = (o + 2 < 32) ? o + 2 : 31;

        // p1: tile e (buf0), N-half 0.  Stage buf1 part2 (tile o).
        LOAD_TILE(0);
        stageB2(1, o);
        OPEN_PHASE; QUAD(b0, b1, 0, 1); CLOSE_PHASE;
        // p2: tile e, N-half 1.  Stage buf0 part1 (tile e+2); vmcnt(3) seals buf1.
        stageA(0, e2); stageB1(0, e2);
        asm volatile("s_waitcnt vmcnt(3)" ::: "memory");
        OPEN_PHASE; QUAD(b2, b3, 2, 3); CLOSE_PHASE;
        // p3: tile o (buf1), N-half 0.  Stage buf0 part2 (tile e+2).
        LOAD_TILE(1);
        stageB2(0, e2);
        OPEN_PHASE; QUAD(b0, b1, 0, 1); CLOSE_PHASE;
        // p4: tile o, N-half 1.  Stage buf1 part1 (tile o+2); vmcnt(3) seals buf0.
        stageA(1, o2); stageB1(1, o2);
        asm volatile("s_waitcnt vmcnt(3)" ::: "memory");
        OPEN_PHASE; QUAD(b2, b3, 2, 3); CLOSE_PHASE;
    }
#undef OPEN_PHASE
#undef CLOSE_PHASE
#undef QUAD
#undef LOAD_TILE

    asm volatile("s_waitcnt vmcnt(0)" ::: "memory");   // drain DMA before exit

    const int wr = wm * 64, wc = wn * 64;
    if (z < 2) {
        bf16* Y = (z == 0) ? Qm : Km;
        const float scale = (z == 0) ? 0.1275174396094198f : 1.0f;  // log2e/sqrt(128) | 1
        const int odd = l15 & 1;
#pragma unroll
        for (int mi = 0; mi < 4; ++mi) {
            int r0 = rbase + wr + mi * 16 + l4 * 4;
#pragma unroll
            for (int i = 0; i < 4; ++i) {
                int r = r0 + i;
                int b = r >> 11, s = r & 2047;
#pragma unroll
                for (int ni = 0; ni < 4; ++ni) {
                    int n = cbase + wc + ni * 16 + l15;
                    int h = n >> 7, d = n & 127;
                    float v = acc[mi][ni][i];
                    float p = __shfl_xor(v, 1);
                    float2 cs = tbl[(s << 6) + (d >> 1)];
                    float res = v * cs.x + (odd ? p : -p) * cs.y;
                    Y[(((size_t)b * 16 + h) * 2048 + s) * 128 + d] = f2b(res * scale);
                }
            }
        }
    } else {
#pragma unroll
        for (int mi = 0; mi < 4; ++mi) {
            int r0 = rbase + wr + mi * 16 + l4 * 4;
            int b = r0 >> 11, s = r0 & 2047;
#pragma unroll
            for (int ni = 0; ni < 4; ++ni) {
                int n = cbase + wc + ni * 16 + l15;
                int h = n >> 7, d = n & 127;
                bf16x4 o;
#pragma unroll
                for (int i = 0; i < 4; ++i) o[i] = f2b(acc[mi][ni][i]);
                *reinterpret_cast<bf16x4*>(&Vt[(((size_t)b * 16 + h) * 128 + d) * 2048 + s]) = o;
            }
        }
    }
}

// ---------------- causal flash attention v4 (unchanged) ----------------
__global__ __launch_bounds__(256) void flash_attn(const bf16* __restrict__ Q,
                                                  const bf16* __restrict__ Km,
                                                  const bf16* __restrict__ Vt,
                                                  float* __restrict__ out) {
    __shared__ bf16 Ksh[64 * 128];
    __shared__ bf16 Vsh[128 * 64];
    __shared__ bf16 Psh[4][16 * 64];

    const int tid  = threadIdx.x;
    const int lane = tid & 63;
    const int w    = tid >> 6;
    const int l15  = lane & 15;
    const int l4   = lane >> 4;

    const int bx  = blockIdx.x;
    const int g   = (bx >> 5) & 7;
    const int seg = bx >> 8;
    const int qt  = (seg == 0) ? 31 - g : (seg == 1) ? g : (seg == 2) ? 23 - g : 8 + g;
    const int bh  = bx & 31;
    const int b   = bh >> 4, h = bh & 15;

    const bf16* Qb = Q  + (size_t)bh * 2048 * 128;
    const bf16* Kb = Km + (size_t)bh * 2048 * 128;
    const bf16* Vb = Vt + (size_t)bh * 128 * 2048;
    const int rw = qt * 64 + w * 16;

    auto stage = [&](int kvb) {
#pragma unroll
        for (int c4 = 0; c4 < 4; ++c4) {
            int c  = w * 4 + c4;
            int kr = c * 4 + (lane >> 4);
            int ks = (lane & 15) ^ (kr & 7);
            gload16((const char*)Kb + ((size_t)(kvb + kr) * 128 + ks * 8) * 2,
                    (char*)Ksh + c * 1024);
            int vr = c * 8 + (lane >> 3);
            int vs = (lane & 7) ^ (vr & 7);
            gload16((const char*)Vb + ((size_t)vr * 2048 + kvb + vs * 8) * 2,
                    (char*)Vsh + c * 1024);
        }
    };

    bf16x8 qf[4];
#pragma unroll
    for (int ks = 0; ks < 4; ++ks)
        qf[ks] = *reinterpret_cast<const bf16x8*>(
            &Qb[(size_t)(rw + l15) * 128 + ks * 32 + l4 * 8]);

    f32x4 o[8] = {};
    float mrow[4], lrow[4];
#pragma unroll
    for (int i = 0; i < 4; ++i) { mrow[i] = -1e30f; lrow[i] = 0.0f; }

    char* pw = (char*)Psh[w];

    for (int t = 0; t <= qt; ++t) {
        const int kvb = t * 64;
        __syncthreads();
        stage(kvb);
        __syncthreads();

        const char* kb = (const char*)Ksh;
        f32x4 sacc[4] = {};
        __builtin_amdgcn_s_setprio(1);
#pragma unroll
        for (int ns = 0; ns < 4; ++ns) {
            int r = ns * 16 + l15;
#pragma unroll
            for (int ks = 0; ks < 4; ++ks) {
                int phys = (ks * 4 + l4) ^ (r & 7);
                bf16x8 kf = *reinterpret_cast<const bf16x8*>(kb + r * 256 + phys * 16);
                sacc[ns] = MFMA16(qf[ks], kf, sacc[ns]);
            }
        }
        __builtin_amdgcn_s_setprio(0);

        if (t == qt) {
#pragma unroll
            for (int ns = 0; ns < 4; ++ns) {
                int col = kvb + ns * 16 + l15;
#pragma unroll
                for (int i = 0; i < 4; ++i) {
                    int row = rw + l4 * 4 + i;
                    if (col > row) sacc[ns][i] = -1e30f;
                }
            }
        }
#pragma unroll
        for (int i = 0; i < 4; ++i) {
            float sm = fmaxf(fmaxf(sacc[0][i], sacc[1][i]), fmaxf(sacc[2][i], sacc[3][i]));
            sm = fmaxf(sm, __shfl_xor(sm, 1));
            sm = fmaxf(sm, __shfl_xor(sm, 2));
            sm = fmaxf(sm, __shfl_xor(sm, 4));
            sm = fmaxf(sm, __shfl_xor(sm, 8));
            float nm    = fmaxf(mrow[i], sm);
            float alpha = __builtin_amdgcn_exp2f(mrow[i] - nm);
            mrow[i] = nm;
            float ps = 0.0f;
            int r = l4 * 4 + i;
            int f = r & 7;
#pragma unroll
            for (int ns = 0; ns < 4; ++ns) {
                float p = __builtin_amdgcn_exp2f(sacc[ns][i] - nm);
                ps += p;
                int col  = ns * 16 + l15;
                int slot = (col >> 3) ^ f;
                *(bf16*)(pw + r * 128 + slot * 16 + (col & 7) * 2) = f2b(p);
            }
            ps += __shfl_xor(ps, 1);
            ps += __shfl_xor(ps, 2);
            ps += __shfl_xor(ps, 4);
            ps += __shfl_xor(ps, 8);
            lrow[i] = lrow[i] * alpha + ps;
#pragma unroll
            for (int ds = 0; ds < 8; ++ds) o[ds][i] *= alpha;
        }
        asm volatile("s_waitcnt lgkmcnt(0)" ::: "memory");
        __builtin_amdgcn_sched_barrier(0);
        const char* vb = (const char*)Vsh;
        __builtin_amdgcn_s_setprio(1);
#pragma unroll
        for (int k2 = 0; k2 < 2; ++k2) {
            int pr   = l15;
            int phys = (k2 * 4 + l4) ^ (pr & 7);
            bf16x8 pa = *reinterpret_cast<const bf16x8*>(pw + pr * 128 + phys * 16);
#pragma unroll
            for (int ds = 0; ds < 8; ++ds) {
                int d     = ds * 16 + l15;
                int physv = (k2 * 4 + l4) ^ (d & 7);
                bf16x8 vf = *reinterpret_cast<const bf16x8*>(vb + d * 128 + physv * 16);
                o[ds] = MFMA16(pa, vf, o[ds]);
            }
        }
        __builtin_amdgcn_s_setprio(0);
    }

#pragma unroll
    for (int i = 0; i < 4; ++i) {
        float inv = 1.0f / lrow[i];
        int row = rw + l4 * 4 + i;
#pragma unroll
        for (int ds = 0; ds < 8; ++ds)
            out[((size_t)b * 2048 + row) * 2048 + h * 128 + ds * 16 + l15] = o[ds][i] * inv;
    }
}

extern "C" void kernel_launch(void* const* d_in, const int* in_sizes, int n_in,
                              void* d_out, int out_size, void* d_ws, size_t ws_size,
                              hipStream_t stream) {
    const float* x  = (const float*)d_in[0];
    const float* Wq = (const float*)d_in[1];
    const float* Wk = (const float*)d_in[2];
    const float* Wv = (const float*)d_in[3];
    float* out = (float*)d_out;
    char* ws = (char*)d_ws;

    bf16* xb   = (bf16*)(ws + 0);
    bf16* wqb  = (bf16*)(ws + 16777216);
    bf16* wkb  = (bf16*)(ws + 25165824);
    bf16* wvb  = (bf16*)(ws + 33554432);
    bf16* Qm   = (bf16*)(ws + 41943040);
    bf16* Km   = (bf16*)(ws + 58720256);
    bf16* Vt   = (bf16*)(ws + 75497472);
    float2* tbl = (float2*)(ws + 92274688);

    cvt_all<<<20480, 256, 0, stream>>>(x, Wq, Wk, Wv, xb, wqb, wkb, wvb);
    rope_table<<<512, 256, 0, stream>>>(tbl);

    gemm_qkv<<<768, 512, 0, stream>>>(xb, wqb, wkb, wvb, Qm, Km, Vt, tbl);

    flash_attn<<<1024, 256, 0, stream>>>(Qm, Km, Vt, out);
}

// Round 9
// 216.214 us; speedup vs baseline: 1.1527x; 1.1124x over previous
//
#include <hip/hip_runtime.h>
#include <hip/hip_bf16.h>
#include <stdint.h>

typedef __bf16 bf16;
typedef bf16 bf16x8 __attribute__((ext_vector_type(8)));
typedef bf16 bf16x4 __attribute__((ext_vector_type(4)));
typedef float f32x4 __attribute__((ext_vector_type(4)));

#define MFMA16(a, b, c) __builtin_amdgcn_mfma_f32_16x16x32_bf16(a, b, c, 0, 0, 0)

static __device__ __forceinline__ bf16 f2b(float f) { return (bf16)f; }
static __device__ __forceinline__ float b2f(bf16 v) { return (float)v; }

// async global->LDS, 16B per lane. dst is wave-uniform base; HW adds lane*16.
static __device__ __forceinline__ void gload16(const void* src, void* dst) {
    __builtin_amdgcn_global_load_lds(
        (const __attribute__((address_space(1))) uint32_t*)src,
        (__attribute__((address_space(3))) uint32_t*)dst, 16, 0, 0);
}

// pack 2 f32 -> u32 of 2 bf16 (lo = src0, hi = src1); no builtin on gfx950
static __device__ __forceinline__ uint32_t cvtpk(float lo, float hi) {
    uint32_t r;
    asm volatile("v_cvt_pk_bf16_f32 %0, %1, %2" : "=v"(r) : "v"(lo), "v"(hi));
    return r;
}

// ---------------- fused fp32 -> bf16 conversion ----------------
__global__ void cvt_all(const float* __restrict__ x,  const float* __restrict__ wq,
                        const float* __restrict__ wk, const float* __restrict__ wv,
                        bf16* __restrict__ xb,  bf16* __restrict__ wqb,
                        bf16* __restrict__ wkb, bf16* __restrict__ wvb) {
    int i = blockIdx.x * blockDim.x + threadIdx.x;
    const float* src; bf16* dst; int off;
    if (i < 2097152)      { src = x;  dst = xb;  off = i; }
    else if (i < 3145728) { src = wq; dst = wqb; off = i - 2097152; }
    else if (i < 4194304) { src = wk; dst = wkb; off = i - 3145728; }
    else                  { src = wv; dst = wvb; off = i - 4194304; }
    float4 v = reinterpret_cast<const float4*>(src)[off];
    bf16x4 o;
    o[0] = f2b(v.x); o[1] = f2b(v.y); o[2] = f2b(v.z); o[3] = f2b(v.w);
    reinterpret_cast<bf16x4*>(dst)[off] = o;
}

// ---------------- RoPE cos/sin table ----------------
__global__ void rope_table(float2* __restrict__ tbl) {
    int t = blockIdx.x * blockDim.x + threadIdx.x;
    int i = t & 63;
    int s = t >> 6;
    float theta = expf(-9.210340371976184f * (float)(2 * i) * (1.0f / 128.0f));
    float freq = (float)s * theta;
    float sv, cv;
    sincosf(freq, &sv, &cv);
    tbl[t] = make_float2(cv, sv);
}

// ---------------- fused QKV GEMM (round-6 2-phase dbuf: best measured) ------------
__global__ __launch_bounds__(256) void gemm_qkv(const bf16* __restrict__ X,
                                                const bf16* __restrict__ Wq,
                                                const bf16* __restrict__ Wk,
                                                const bf16* __restrict__ Wv,
                                                bf16* __restrict__ Qm,
                                                bf16* __restrict__ Km,
                                                bf16* __restrict__ Vt,
                                                const float2* __restrict__ tbl) {
    const int K = 2048;
    __shared__ bf16 As[2][128 * 64];
    __shared__ bf16 Bs[2][128 * 64];

    const int z = blockIdx.z;
    const bf16* W = (z == 0) ? Wq : (z == 1) ? Wk : Wv;

    const int tid  = threadIdx.x;
    const int lane = tid & 63;
    const int w    = tid >> 6;
    const int wr   = (w >> 1) * 64;
    const int wc   = (w & 1) * 64;
    const int l15  = lane & 15;
    const int l4   = lane >> 4;
    const int rbase = blockIdx.x * 128;
    const int cbase = blockIdx.y * 128;

    const int srow  = lane >> 3;
    const int sslot = lane & 7;

    f32x4 acc[4][4] = {};

    auto stage = [&](int buf, int kt) {
#pragma unroll
        for (int i = 0; i < 4; ++i) {
            int c   = w * 4 + i;
            int row = c * 8 + srow;
            int gsl = sslot ^ (row & 7);
            gload16(&X[(size_t)(rbase + row) * K + kt + gsl * 8], (char*)As[buf] + c * 1024);
            gload16(&W[(size_t)(cbase + row) * K + kt + gsl * 8], (char*)Bs[buf] + c * 1024);
        }
    };

    stage(0, 0);
    __syncthreads();
    int cur = 0;

    for (int kt = 0; kt < K; kt += 64) {
        if (kt + 64 < K) stage(cur ^ 1, kt + 64);

        bf16x8 af[2][4], bfr[2][4];
#pragma unroll
        for (int ks = 0; ks < 2; ++ks) {
#pragma unroll
            for (int mi = 0; mi < 4; ++mi) {
                int r    = wr + mi * 16 + l15;
                int phys = (ks * 4 + l4) ^ (r & 7);
                af[ks][mi] = *reinterpret_cast<const bf16x8*>(
                    (char*)As[cur] + r * 128 + phys * 16);
            }
#pragma unroll
            for (int ni = 0; ni < 4; ++ni) {
                int r    = wc + ni * 16 + l15;
                int phys = (ks * 4 + l4) ^ (r & 7);
                bfr[ks][ni] = *reinterpret_cast<const bf16x8*>(
                    (char*)Bs[cur] + r * 128 + phys * 16);
            }
        }
#pragma unroll
        for (int ks = 0; ks < 2; ++ks)
#pragma unroll
            for (int mi = 0; mi < 4; ++mi)
#pragma unroll
                for (int ni = 0; ni < 4; ++ni)
                    acc[mi][ni] = MFMA16(af[ks][mi], bfr[ks][ni], acc[mi][ni]);

        __syncthreads();
        cur ^= 1;
    }

    if (z < 2) {
        bf16* Y = (z == 0) ? Qm : Km;
        const float scale = (z == 0) ? 0.1275174396094198f : 1.0f;  // log2e/sqrt(128) | 1
        const int odd = l15 & 1;
#pragma unroll
        for (int mi = 0; mi < 4; ++mi) {
            int r0 = rbase + wr + mi * 16 + l4 * 4;
#pragma unroll
            for (int i = 0; i < 4; ++i) {
                int r = r0 + i;
                int b = r >> 11, s = r & 2047;
#pragma unroll
                for (int ni = 0; ni < 4; ++ni) {
                    int n = cbase + wc + ni * 16 + l15;
                    int h = n >> 7, d = n & 127;
                    float v = acc[mi][ni][i];
                    float p = __shfl_xor(v, 1);
                    float2 cs = tbl[(s << 6) + (d >> 1)];
                    float res = v * cs.x + (odd ? p : -p) * cs.y;
                    Y[(((size_t)b * 16 + h) * 2048 + s) * 128 + d] = f2b(res * scale);
                }
            }
        }
    } else {
#pragma unroll
        for (int mi = 0; mi < 4; ++mi) {
            int r0 = rbase + wr + mi * 16 + l4 * 4;
            int b = r0 >> 11, s = r0 & 2047;
#pragma unroll
            for (int ni = 0; ni < 4; ++ni) {
                int n = cbase + wc + ni * 16 + l15;
                int h = n >> 7, d = n & 127;
                bf16x4 o;
#pragma unroll
                for (int i = 0; i < 4; ++i) o[i] = f2b(acc[mi][ni][i]);
                *reinterpret_cast<bf16x4*>(&Vt[(((size_t)b * 16 + h) * 128 + d) * 2048 + s]) = o;
            }
        }
    }
}

// ---------------- causal flash attention v5: swapped QK^T + in-register P -------------
// S^T = mfma(A=K, B=Q): lane l15 owns q-row (rw+l15); its 16 scores live in
// s4[t4][i] with k = kvb + t4*16 + l4*4 + i. Softmax = in-lane trees + 2 shfl_xor.
// P packed via v_cvt_pk_bf16_f32, redistributed to PV A-fragment layout with
// 16 ds_bpermute + 8 selects (no P LDS, no lgkmcnt drain). LDS 32KB -> 5 blk/CU.
__global__ __launch_bounds__(256, 4) void flash_attn(const bf16* __restrict__ Q,
                                                     const bf16* __restrict__ Km,
                                                     const bf16* __restrict__ Vt,
                                                     float* __restrict__ out) {
    __shared__ bf16 Ksh[64 * 128];    // 16KB, swizzled 16B slots
    __shared__ bf16 Vsh[128 * 64];    // 16KB, swizzled

    const int tid  = threadIdx.x;
    const int lane = tid & 63;
    const int w    = tid >> 6;
    const int l15  = lane & 15;
    const int l4   = lane >> 4;       // L (0..3)

    const int bx  = blockIdx.x;
    const int g   = (bx >> 5) & 7;
    const int seg = bx >> 8;
    const int qt  = (seg == 0) ? 31 - g : (seg == 1) ? g : (seg == 2) ? 23 - g : 8 + g;
    const int bh  = bx & 31;
    const int b   = bh >> 4, h = bh & 15;

    const bf16* Qb = Q  + (size_t)bh * 2048 * 128;
    const bf16* Kb = Km + (size_t)bh * 2048 * 128;
    const bf16* Vb = Vt + (size_t)bh * 128 * 2048;
    const int rw = qt * 64 + w * 16;

    auto stage = [&](int kvb) {
#pragma unroll
        for (int c4 = 0; c4 < 4; ++c4) {
            int c  = w * 4 + c4;
            int kr = c * 4 + (lane >> 4);
            int ks = (lane & 15) ^ (kr & 7);
            gload16((const char*)Kb + ((size_t)(kvb + kr) * 128 + ks * 8) * 2,
                    (char*)Ksh + c * 1024);
            int vr = c * 8 + (lane >> 3);
            int vs = (lane & 7) ^ (vr & 7);
            gload16((const char*)Vb + ((size_t)vr * 2048 + kvb + vs * 8) * 2,
                    (char*)Vsh + c * 1024);
        }
    };

    bf16x8 qf[4];
#pragma unroll
    for (int ks = 0; ks < 4; ++ks)
        qf[ks] = *reinterpret_cast<const bf16x8*>(
            &Qb[(size_t)(rw + l15) * 128 + ks * 32 + l4 * 8]);

    f32x4 o[8] = {};
    float mrow = -1e30f, lrow = 0.0f;     // state for q-row rw + l15

    const int xbase = l15 + ((lane >> 4) & 1) * 32;   // bpermute src base
    const bool hiL  = (lane >> 5) & 1;                // L>>1

    for (int t = 0; t <= qt; ++t) {
        const int kvb = t * 64;
        __syncthreads();
        stage(kvb);
        __syncthreads();

        const char* kb = (const char*)Ksh;
        f32x4 s4[4] = {};                 // s4[t4][i]: k = kvb + t4*16 + l4*4 + i
        __builtin_amdgcn_s_setprio(1);
#pragma unroll
        for (int t4 = 0; t4 < 4; ++t4) {
            int r = t4 * 16 + l15;
#pragma unroll
            for (int ks = 0; ks < 4; ++ks) {
                int phys = (ks * 4 + l4) ^ (r & 7);
                bf16x8 kf = *reinterpret_cast<const bf16x8*>(kb + r * 256 + phys * 16);
                s4[t4] = MFMA16(kf, qf[ks], s4[t4]);   // swapped: A=K, B=Q
            }
        }
        __builtin_amdgcn_s_setprio(0);

        if (t == qt) {   // causal mask: k > q
            int q = rw + l15;
#pragma unroll
            for (int t4 = 0; t4 < 4; ++t4)
#pragma unroll
                for (int i = 0; i < 4; ++i)
                    if (kvb + t4 * 16 + l4 * 4 + i > q) s4[t4][i] = -1e30f;
        }

        // in-lane softmax (exp2 domain; scores pre-scaled by log2e/sqrt(d))
        float sm = -1e30f;
#pragma unroll
        for (int t4 = 0; t4 < 4; ++t4)
#pragma unroll
            for (int i = 0; i < 4; ++i) sm = fmaxf(sm, s4[t4][i]);
        sm = fmaxf(sm, __shfl_xor(sm, 16));
        sm = fmaxf(sm, __shfl_xor(sm, 32));
        float nm    = fmaxf(mrow, sm);
        float alpha = __builtin_amdgcn_exp2f(mrow - nm);
        mrow = nm;
        float ps = 0.0f;
#pragma unroll
        for (int t4 = 0; t4 < 4; ++t4)
#pragma unroll
            for (int i = 0; i < 4; ++i) {
                float p = __builtin_amdgcn_exp2f(s4[t4][i] - nm);
                s4[t4][i] = p;
                ps += p;
            }
        ps += __shfl_xor(ps, 16);
        ps += __shfl_xor(ps, 32);
        lrow = lrow * alpha + ps;

        // rescale o: alpha of q' = l4*4+i lives in lane (lane&48)+(l4*4+i)
        float ai[4];
#pragma unroll
        for (int i = 0; i < 4; ++i)
            ai[i] = __shfl(alpha, (lane & 48) + l4 * 4 + i);
#pragma unroll
        for (int ds = 0; ds < 8; ++ds)
#pragma unroll
            for (int i = 0; i < 4; ++i) o[ds][i] *= ai[i];

        // pack P to bf16 pairs: own[t4*2+h] = {P[t4][2h] lo, P[t4][2h+1] hi}
        uint32_t own[8];
#pragma unroll
        for (int t4 = 0; t4 < 4; ++t4) {
            own[t4 * 2 + 0] = cvtpk(s4[t4][0], s4[t4][1]);
            own[t4 * 2 + 1] = cvtpk(s4[t4][2], s4[t4][3]);
        }
        // redistribute to PV A-frag: pa[ks2] = P[q=l15][k = ks2*32 + L*8 + j]
        bf16x8 pa[2];
#pragma unroll
        for (int ks2 = 0; ks2 < 2; ++ks2) {
            union { uint32_t u[4]; bf16x8 v; } pu;
#pragma unroll
            for (int s = 0; s < 4; ++s) {
                int srcl = xbase + 16 * (s >> 1);
                uint32_t ulo = (uint32_t)__shfl((int)own[ks2 * 4 + (s & 1)], srcl);
                uint32_t uhi = (uint32_t)__shfl((int)own[ks2 * 4 + 2 + (s & 1)], srcl);
                pu.u[s] = hiL ? uhi : ulo;
            }
            pa[ks2] = pu.v;
        }

        // PV: O += P @ V
        const char* vb = (const char*)Vsh;
        __builtin_amdgcn_s_setprio(1);
#pragma unroll
        for (int k2 = 0; k2 < 2; ++k2) {
#pragma unroll
            for (int ds = 0; ds < 8; ++ds) {
                int d     = ds * 16 + l15;
                int physv = (k2 * 4 + l4) ^ (d & 7);
                bf16x8 vf = *reinterpret_cast<const bf16x8*>(vb + d * 128 + physv * 16);
                o[ds] = MFMA16(pa[k2], vf, o[ds]);
            }
        }
        __builtin_amdgcn_s_setprio(0);
    }

    // epilogue: normalize + store fp32 (row q' = rw + l4*4 + i)
    float inv = 1.0f / lrow;
    float iv[4];
#pragma unroll
    for (int i = 0; i < 4; ++i)
        iv[i] = __shfl(inv, (lane & 48) + l4 * 4 + i);
#pragma unroll
    for (int i = 0; i < 4; ++i) {
        int row = rw + l4 * 4 + i;
#pragma unroll
        for (int ds = 0; ds < 8; ++ds)
            out[((size_t)b * 2048 + row) * 2048 + h * 128 + ds * 16 + l15] =
                o[ds][i] * iv[i];
    }
}

extern "C" void kernel_launch(void* const* d_in, const int* in_sizes, int n_in,
                              void* d_out, int out_size, void* d_ws, size_t ws_size,
                              hipStream_t stream) {
    const float* x  = (const float*)d_in[0];
    const float* Wq = (const float*)d_in[1];
    const float* Wk = (const float*)d_in[2];
    const float* Wv = (const float*)d_in[3];
    float* out = (float*)d_out;
    char* ws = (char*)d_ws;

    bf16* xb   = (bf16*)(ws + 0);
    bf16* wqb  = (bf16*)(ws + 16777216);
    bf16* wkb  = (bf16*)(ws + 25165824);
    bf16* wvb  = (bf16*)(ws + 33554432);
    bf16* Qm   = (bf16*)(ws + 41943040);
    bf16* Km   = (bf16*)(ws + 58720256);
    bf16* Vt   = (bf16*)(ws + 75497472);
    float2* tbl = (float2*)(ws + 92274688);

    cvt_all<<<20480, 256, 0, stream>>>(x, Wq, Wk, Wv, xb, wqb, wkb, wvb);
    rope_table<<<512, 256, 0, stream>>>(tbl);

    dim3 gg(32, 16, 3);
    gemm_qkv<<<gg, 256, 0, stream>>>(xb, wqb, wkb, wvb, Qm, Km, Vt, tbl);

    flash_attn<<<1024, 256, 0, stream>>>(Qm, Km, Vt, out);
}